// Round 1
// 2064.220 us; speedup vs baseline: 1.0896x; 1.0896x over previous
//
#include <hip/hip_runtime.h>

#define N_NODES 50000
#define L_SCALES 4
#define E_NNZ 1600000
#define C 128
#define NL (N_NODES * L_SCALES)

#define ELL_W 64
#define OVF_CAP 8192

#define RPB 16                    // rows per bucket
#define NB (N_NODES / RPB)        // 3125 buckets (exact)
#define NSUB 8                    // per-XCD sub-regions
#define SCAP 112                  // capacity per (sub, bucket); mean 64, sigma 8
#define GROUP 4                   // buckets per workgroup in pass 2
#define BT_STRIDE 16              // pad tail counters to one per 64B line

// ---------------- Fused GEMM over all scales: out[r,c] = sum_k feat[r,k]*W[k,c], r in [0, N*L) ----------------
__global__ __launch_bounds__(256) void gemm_all(
    const float* __restrict__ feat,   // [NL, C]
    const float* __restrict__ W,      // [C, C]
    float* __restrict__ Y)            // [NL, C]  (aliases d_out)
{
    __shared__ float Ws[32 * C];      // 16 KB k-tile of W
    __shared__ float Xs[16 * C];      // 8 KB: 16 feature rows

    int t = threadIdx.x;
    int row0 = blockIdx.x * 16;       // NL/16 = 12500 exact

    for (int i = t; i < 16 * C; i += 256)
        Xs[i] = feat[((size_t)row0 + (i >> 7)) * C + (i & 127)];

    int rr = t >> 4;
    int c0 = (t & 15) * 8;
    float acc[8] = {0.f, 0.f, 0.f, 0.f, 0.f, 0.f, 0.f, 0.f};

    for (int kt = 0; kt < 4; ++kt) {
        __syncthreads();
        for (int i = t; i < 32 * C; i += 256)
            Ws[i] = W[kt * 32 * C + i];
        __syncthreads();
        #pragma unroll
        for (int k = 0; k < 32; ++k) {
            float x = Xs[rr * C + kt * 32 + k];
            #pragma unroll
            for (int j = 0; j < 8; ++j)
                acc[j] += x * Ws[k * C + c0 + j];
        }
    }

    #pragma unroll
    for (int j = 0; j < 8; ++j)
        Y[((size_t)row0 + rr) * C + c0 + j] = acc[j];
}

// ---------------- Pass 1: partition edges into 16-row buckets, packed 8B records ----------------
__global__ __launch_bounds__(256) void partition_edges(
    const int*   __restrict__ rows,
    const int*   __restrict__ cols,
    const float* __restrict__ vals,
    uint2* __restrict__ bkt,          // [NSUB][NB][SCAP]
    int*   __restrict__ btail,        // [NSUB][NB] stride BT_STRIDE
    int* __restrict__ ovf_n, int* __restrict__ ovf_row,
    int* __restrict__ ovf_col, float* __restrict__ ovf_val)
{
    int e = blockIdx.x * 256 + threadIdx.x;
    if (e >= E_NNZ) return;
    int s = blockIdx.x & (NSUB - 1);  // heuristic XCD id: same-s blocks share an XCD L2
    int r = rows[e];
    int c = cols[e];
    float v = vals[e];
    int b = r >> 4;                   // RPB = 16
    int pos = atomicAdd(&btail[(s * NB + b) * BT_STRIDE], 1);
    if (pos < SCAP) {
        // col fits in 16 bits (N=50000 < 65536); rowlo in bits 16..19
        bkt[((size_t)s * NB + b) * SCAP + pos] =
            make_uint2((unsigned)c | ((unsigned)(r & (RPB - 1)) << 16), __float_as_uint(v));
    } else {                          // statistically never (z ≈ 6σ); correctness fallback
        int k = atomicAdd(ovf_n, 1);
        if (k < OVF_CAP) { ovf_row[k] = r; ovf_col[k] = c; ovf_val[k] = v; }
    }
}

// ---------------- Pass 2: build packed ELL (uint2 {col, val}) in LDS, flush coalesced ----------------
__global__ __launch_bounds__(256) void ell_from_buckets(
    const uint2* __restrict__ bkt,
    const int*   __restrict__ btail,
    uint2* __restrict__ ell,          // [N][ELL_W]
    int*   __restrict__ cnt,          // [N]
    int* __restrict__ ovf_n, int* __restrict__ ovf_row,
    int* __restrict__ ovf_col, float* __restrict__ ovf_val)
{
    __shared__ __align__(16) uint2 ell_s[GROUP * RPB][ELL_W];   // 64 x 64 x 8B = 32 KB
    __shared__ int lcnt[GROUP * RPB];

    int t  = threadIdx.x;
    int b0 = blockIdx.x * GROUP;
    int r0 = b0 * RPB;

    if (t < GROUP * RPB) lcnt[t] = 0;
    __syncthreads();

    for (int g = 0; g < GROUP; ++g) {
        int b = b0 + g;
        if (b >= NB) break;           // grid covers 3128 buckets, NB=3125
        for (int s = 0; s < NSUB; ++s) {
            int n = btail[(s * NB + b) * BT_STRIDE];
            if (n > SCAP) n = SCAP;
            for (int i = t; i < n; i += 256) {
                uint2 rec = bkt[((size_t)s * NB + b) * SCAP + i];
                int lr = g * RPB + (int)(rec.x >> 16);
                int pos = atomicAdd(&lcnt[lr], 1);
                if (pos < ELL_W) {
                    ell_s[lr][pos] = make_uint2(rec.x & 0xFFFFu, rec.y);
                } else {              // row degree > 64: ~never (z ≈ 5.7σ)
                    int k = atomicAdd(ovf_n, 1);
                    if (k < OVF_CAP) {
                        ovf_row[k] = r0 + lr;
                        ovf_col[k] = (int)(rec.x & 0xFFFFu);
                        ovf_val[k] = __uint_as_float(rec.y);
                    }
                }
            }
        }
    }
    __syncthreads();

    // Coalesced flush: 64 rows x 64 slots of uint2 = 32 KB, as uint4 (unused slots = don't-care,
    // spmm only broadcasts slots j < min(cnt, ELL_W)).
    const uint4* src = (const uint4*)&ell_s[0][0];
    for (int i = t; i < GROUP * RPB * (ELL_W / 2); i += 256) {   // 2048 uint4
        int row = r0 + (i >> 5);
        if (row < N_NODES)
            ((uint4*)ell)[(size_t)row * (ELL_W / 2) + (i & 31)] = src[i];
    }
    if (t < GROUP * RPB) {
        int row = r0 + t;
        if (row < N_NODES) cnt[row] = lcnt[t];
    }
}

// ---------------- SpMM (gather): out[row] = scale * sum_e val_e * X[col_e] ----------------
__global__ __launch_bounds__(256) void spmm_ell(
    const uint2* __restrict__ ell,
    const int*   __restrict__ cnt,
    const int*   __restrict__ ovf_n,
    const int*   __restrict__ ovf_row,
    const int*   __restrict__ ovf_col,
    const float* __restrict__ ovf_val,
    const float* __restrict__ X,          // row stride x_stride
    const float* __restrict__ row_scale,  // nullptr or theta[N]
    float*       __restrict__ out,        // row stride out_stride
    int x_stride, int out_stride)
{
    int row  = (blockIdx.x * 256 + threadIdx.x) >> 6;   // grid exact: 12500 wg x 4 rows
    int lane = threadIdx.x & 63;

    int n   = cnt[row];
    int ncl = n < ELL_W ? n : ELL_W;

    uint2 rec = make_uint2(0u, 0u);
    if (lane < ncl) rec = ell[(size_t)row * ELL_W + lane];  // masked: skip unused slots
    int   mycol = (int)rec.x;
    float myval = __uint_as_float(rec.y);

    float2 acc = {0.f, 0.f};
    for (int j = 0; j < ncl; ++j) {
        int   c = __shfl(mycol, j);
        float v = __shfl(myval, j);
        float2 x = ((const float2*)(X + (size_t)c * x_stride))[lane];
        acc.x += v * x.x;
        acc.y += v * x.y;
    }

    int m = *ovf_n;                    // expected 0; one hot scalar read per wave
    if (m > 0) {
        if (m > OVF_CAP) m = OVF_CAP;
        for (int k = 0; k < m; ++k) {
            if (ovf_row[k] == row) {
                float v = ovf_val[k];
                float2 x = ((const float2*)(X + (size_t)ovf_col[k] * x_stride))[lane];
                acc.x += v * x.x;
                acc.y += v * x.y;
            }
        }
    }

    if (row_scale) {
        float s = row_scale[row];
        acc.x *= s;
        acc.y *= s;
    }
    ((float2*)(out + (size_t)row * out_stride))[lane] = acc;
}

extern "C" void kernel_launch(void* const* d_in, const int* in_sizes, int n_in,
                              void* d_out, int out_size, void* d_ws, size_t ws_size,
                              hipStream_t stream) {
    const int*   phi_idx  = (const int*)  d_in[0];   // [L, 2, E]
    const float* phi_val  = (const float*)d_in[1];   // [L, E]
    const int*   pinv_idx = (const int*)  d_in[2];   // [L, 2, E]
    const float* pinv_val = (const float*)d_in[3];   // [L, E]
    const float* feat     = (const float*)d_in[4];   // [N, L, C] == [NL, C]
    const float* W        = (const float*)d_in[5];   // [C, C]
    const float* theta    = (const float*)d_in[6];   // [N]
    float* out = (float*)d_out;

    // Workspace layout (~75.5 MB; previous version used ~77.2 MB)
    float* Z       = (float*)d_ws;                               // N*C f32          25.6 MB
    uint2* bkt     = (uint2*)(Z + (size_t)N_NODES * C);          // NSUB*NB*SCAP     22.4 MB
    uint2* ell     = bkt + (size_t)NSUB * NB * SCAP;             // N*ELL_W uint2    25.6 MB
    int*   cnt     = (int*)(ell + (size_t)N_NODES * ELL_W);      // N                 0.2 MB
    int*   btail   = cnt + N_NODES;                              // NSUB*NB*16        1.6 MB
    int*   ovf_n   = btail + NSUB * NB * BT_STRIDE;              // 1 (adjacent for single memset)
    int*   ovf_row = ovf_n + 1;
    int*   ovf_col = ovf_row + OVF_CAP;
    float* ovf_val = (float*)(ovf_col + OVF_CAP);

    dim3 blk(256);
    int gemmGrid = NL / 16;                   // 12500
    int partGrid = (E_NNZ + 255) / 256;       // 6250
    int ellGrid  = (NB + GROUP - 1) / GROUP;  // 782
    int spmmGrid = N_NODES * 64 / 256;        // 12500

    // All four scales' feat @ W in one shot, written into out (scratch; each slice
    // out[:,l,:] is consumed by scale-l spmm-1 strictly before scale-l spmm-2 overwrites it).
    gemm_all<<<gemmGrid, blk, 0, stream>>>(feat, W, out);

    for (int l = 0; l < L_SCALES; ++l) {
        // ---- Z = theta ⊙ (phi_inv_l @ out[:,l,:]) ----
        hipMemsetAsync(btail, 0, (NSUB * NB * BT_STRIDE + 1) * sizeof(int), stream);
        partition_edges<<<partGrid, blk, 0, stream>>>(
            pinv_idx + (size_t)l * 2 * E_NNZ,
            pinv_idx + (size_t)l * 2 * E_NNZ + E_NNZ,
            pinv_val + (size_t)l * E_NNZ,
            bkt, btail, ovf_n, ovf_row, ovf_col, ovf_val);
        ell_from_buckets<<<ellGrid, blk, 0, stream>>>(
            bkt, btail, ell, cnt, ovf_n, ovf_row, ovf_col, ovf_val);
        spmm_ell<<<spmmGrid, blk, 0, stream>>>(
            ell, cnt, ovf_n, ovf_row, ovf_col, ovf_val,
            out + (size_t)l * C, theta, Z, L_SCALES * C, C);

        // ---- out[:,l,:] = phi_l @ Z ----
        hipMemsetAsync(btail, 0, (NSUB * NB * BT_STRIDE + 1) * sizeof(int), stream);
        partition_edges<<<partGrid, blk, 0, stream>>>(
            phi_idx + (size_t)l * 2 * E_NNZ,
            phi_idx + (size_t)l * 2 * E_NNZ + E_NNZ,
            phi_val + (size_t)l * E_NNZ,
            bkt, btail, ovf_n, ovf_row, ovf_col, ovf_val);
        ell_from_buckets<<<ellGrid, blk, 0, stream>>>(
            bkt, btail, ell, cnt, ovf_n, ovf_row, ovf_col, ovf_val);
        spmm_ell<<<spmmGrid, blk, 0, stream>>>(
            ell, cnt, ovf_n, ovf_row, ovf_col, ovf_val,
            Z, nullptr, out + (size_t)l * C, C, L_SCALES * C);
    }
}

// Round 2
// 1980.940 us; speedup vs baseline: 1.1354x; 1.0420x over previous
//
#include <hip/hip_runtime.h>

#define N_NODES 50000
#define L_SCALES 4
#define E_NNZ 1600000
#define C 128
#define NL (N_NODES * L_SCALES)

#define ELL_W 64
#define OVF_CAP 8192

#define RPB 16                    // rows per bucket
#define NB (N_NODES / RPB)        // 3125 buckets (exact)
#define NSUB 8                    // per-XCD sub-regions
#define SCAP 112                  // capacity per (sub, bucket); mean 64, sigma 8
#define GROUP 4                   // buckets per workgroup in pass 2
#define BT_STRIDE 16              // pad tail counters to one per 64B line

// ---------------- Fused GEMM over all scales: Y[r,c] = sum_k feat[r,k]*W[k,c], r in [0, N*L) ----------------
// lane = row (64 rows/block shared by 4 waves), wave = 32-col slice.
// W reads are wave-uniform -> s_load (scalar pipe, free SGPR operand in v_fmac).
// x: one ds_read_b128 per 4 k per lane -> LDS traffic ~40x lower than v1.
__global__ __launch_bounds__(256) void gemm_all(
    const float* __restrict__ feat,   // [NL, C]
    const float* __restrict__ W,      // [C, C]
    float* __restrict__ Y)            // [NL, C]  (aliases d_out)
{
    __shared__ float4 Xs4[64 * 32];   // 64 rows x 128 floats = 32 KB

    int t = threadIdx.x;
    int l = t & 63;                                  // lane = local row
    int c0 = __builtin_amdgcn_readfirstlane((t >> 6) << 5);  // wave's 32-col base (uniform)
    size_t r0 = (size_t)blockIdx.x * 64;             // NL/64 = 3125 blocks exact

    // Coalesced stage of the 64-row feature tile (float4)
    const float4* feat4 = (const float4*)(feat + r0 * C);
    for (int i = t; i < 64 * 32; i += 256)
        Xs4[i] = feat4[i];
    __syncthreads();

    float acc[32];
    #pragma unroll
    for (int j = 0; j < 32; ++j) acc[j] = 0.f;

    for (int kt = 0; kt < C; kt += 8) {
        float4 xa = Xs4[(l << 5) + (kt >> 2)];
        float4 xb = Xs4[(l << 5) + (kt >> 2) + 1];
        float x8[8];
        x8[0] = xa.x; x8[1] = xa.y; x8[2] = xa.z; x8[3] = xa.w;
        x8[4] = xb.x; x8[5] = xb.y; x8[6] = xb.z; x8[7] = xb.w;
        #pragma unroll
        for (int kk = 0; kk < 8; ++kk) {
            const float* wr = W + (size_t)(kt + kk) * C + c0;  // uniform -> s_load
            #pragma unroll
            for (int j = 0; j < 32; ++j)
                acc[j] = fmaf(x8[kk], wr[j], acc[j]);
        }
    }

    float* orow = Y + (r0 + l) * C + c0;
    #pragma unroll
    for (int j4 = 0; j4 < 8; ++j4)
        ((float4*)orow)[j4] = make_float4(acc[4*j4], acc[4*j4+1], acc[4*j4+2], acc[4*j4+3]);
}

// ---------------- Pass 1: partition edges into 16-row buckets, packed 8B records ----------------
__global__ __launch_bounds__(256) void partition_edges(
    const int*   __restrict__ rows,
    const int*   __restrict__ cols,
    const float* __restrict__ vals,
    uint2* __restrict__ bkt,          // [NSUB][NB][SCAP]
    int*   __restrict__ btail,        // [NSUB][NB] stride BT_STRIDE
    int* __restrict__ ovf_n, int* __restrict__ ovf_row,
    int* __restrict__ ovf_col, float* __restrict__ ovf_val)
{
    int e = blockIdx.x * 256 + threadIdx.x;
    if (e >= E_NNZ) return;
    int s = blockIdx.x & (NSUB - 1);  // heuristic XCD id: same-s blocks share an XCD L2
    int r = rows[e];
    int c = cols[e];
    float v = vals[e];
    int b = r >> 4;                   // RPB = 16
    int pos = atomicAdd(&btail[(s * NB + b) * BT_STRIDE], 1);
    if (pos < SCAP) {
        // col fits in 16 bits (N=50000 < 65536); rowlo in bits 16..19
        bkt[((size_t)s * NB + b) * SCAP + pos] =
            make_uint2((unsigned)c | ((unsigned)(r & (RPB - 1)) << 16), __float_as_uint(v));
    } else {                          // statistically never (z ~ 6 sigma); correctness fallback
        int k = atomicAdd(ovf_n, 1);
        if (k < OVF_CAP) { ovf_row[k] = r; ovf_col[k] = c; ovf_val[k] = v; }
    }
}

// ---------------- Pass 2: build packed ELL (uint2 {col, val}) in LDS, flush coalesced ----------------
__global__ __launch_bounds__(256) void ell_from_buckets(
    const uint2* __restrict__ bkt,
    const int*   __restrict__ btail,
    uint2* __restrict__ ell,          // [N][ELL_W]
    int*   __restrict__ cnt,          // [N]
    int* __restrict__ ovf_n, int* __restrict__ ovf_row,
    int* __restrict__ ovf_col, float* __restrict__ ovf_val)
{
    __shared__ __align__(16) uint2 ell_s[GROUP * RPB][ELL_W];   // 64 x 64 x 8B = 32 KB
    __shared__ int lcnt[GROUP * RPB];

    int t  = threadIdx.x;
    int b0 = blockIdx.x * GROUP;
    int r0 = b0 * RPB;

    if (t < GROUP * RPB) lcnt[t] = 0;
    __syncthreads();

    for (int g = 0; g < GROUP; ++g) {
        int b = b0 + g;
        if (b >= NB) break;           // grid covers 3128 buckets, NB=3125
        for (int s = 0; s < NSUB; ++s) {
            int n = btail[(s * NB + b) * BT_STRIDE];
            if (n > SCAP) n = SCAP;
            for (int i = t; i < n; i += 256) {
                uint2 rec = bkt[((size_t)s * NB + b) * SCAP + i];
                int lr = g * RPB + (int)(rec.x >> 16);
                int pos = atomicAdd(&lcnt[lr], 1);
                if (pos < ELL_W) {
                    ell_s[lr][pos] = make_uint2(rec.x & 0xFFFFu, rec.y);
                } else {              // row degree > 64: ~never (z ~ 5.7 sigma)
                    int k = atomicAdd(ovf_n, 1);
                    if (k < OVF_CAP) {
                        ovf_row[k] = r0 + lr;
                        ovf_col[k] = (int)(rec.x & 0xFFFFu);
                        ovf_val[k] = __uint_as_float(rec.y);
                    }
                }
            }
        }
    }
    __syncthreads();

    // Coalesced flush: 64 rows x 64 slots of uint2 = 32 KB, as uint4 (unused slots = don't-care,
    // spmm only broadcasts slots j < min(cnt, ELL_W)).
    const uint4* src = (const uint4*)&ell_s[0][0];
    for (int i = t; i < GROUP * RPB * (ELL_W / 2); i += 256) {   // 2048 uint4
        int row = r0 + (i >> 5);
        if (row < N_NODES)
            ((uint4*)ell)[(size_t)row * (ELL_W / 2) + (i & 31)] = src[i];
    }
    if (t < GROUP * RPB) {
        int row = r0 + t;
        if (row < N_NODES) cnt[row] = lcnt[t];
    }
}

// ---------------- SpMM (gather): out[row] = scale * sum_e val_e * X[col_e] ----------------
__global__ __launch_bounds__(256) void spmm_ell(
    const uint2* __restrict__ ell,
    const int*   __restrict__ cnt,
    const int*   __restrict__ ovf_n,
    const int*   __restrict__ ovf_row,
    const int*   __restrict__ ovf_col,
    const float* __restrict__ ovf_val,
    const float* __restrict__ X,          // row stride x_stride
    const float* __restrict__ row_scale,  // nullptr or theta[N]
    float*       __restrict__ out,        // row stride out_stride
    int x_stride, int out_stride)
{
    int row  = (blockIdx.x * 256 + threadIdx.x) >> 6;   // grid exact: 12500 wg x 4 rows
    int lane = threadIdx.x & 63;

    int n   = cnt[row];
    int ncl = n < ELL_W ? n : ELL_W;

    uint2 rec = make_uint2(0u, 0u);
    if (lane < ncl) rec = ell[(size_t)row * ELL_W + lane];  // masked: skip unused slots
    int   mycol = (int)rec.x;
    float myval = __uint_as_float(rec.y);

    float2 acc = {0.f, 0.f};
    for (int j = 0; j < ncl; ++j) {
        int   c = __shfl(mycol, j);
        float v = __shfl(myval, j);
        float2 x = ((const float2*)(X + (size_t)c * x_stride))[lane];
        acc.x += v * x.x;
        acc.y += v * x.y;
    }

    int m = *ovf_n;                    // expected 0; one hot scalar read per wave
    if (m > 0) {
        if (m > OVF_CAP) m = OVF_CAP;
        for (int k = 0; k < m; ++k) {
            if (ovf_row[k] == row) {
                float v = ovf_val[k];
                float2 x = ((const float2*)(X + (size_t)ovf_col[k] * x_stride))[lane];
                acc.x += v * x.x;
                acc.y += v * x.y;
            }
        }
    }

    if (row_scale) {
        float s = row_scale[row];
        acc.x *= s;
        acc.y *= s;
    }
    ((float2*)(out + (size_t)row * out_stride))[lane] = acc;
}

extern "C" void kernel_launch(void* const* d_in, const int* in_sizes, int n_in,
                              void* d_out, int out_size, void* d_ws, size_t ws_size,
                              hipStream_t stream) {
    const int*   phi_idx  = (const int*)  d_in[0];   // [L, 2, E]
    const float* phi_val  = (const float*)d_in[1];   // [L, E]
    const int*   pinv_idx = (const int*)  d_in[2];   // [L, 2, E]
    const float* pinv_val = (const float*)d_in[3];   // [L, E]
    const float* feat     = (const float*)d_in[4];   // [N, L, C] == [NL, C]
    const float* W        = (const float*)d_in[5];   // [C, C]
    const float* theta    = (const float*)d_in[6];   // [N]
    float* out = (float*)d_out;

    // Workspace layout (~75.5 MB)
    float* Z       = (float*)d_ws;                               // N*C f32          25.6 MB
    uint2* bkt     = (uint2*)(Z + (size_t)N_NODES * C);          // NSUB*NB*SCAP     22.4 MB
    uint2* ell     = bkt + (size_t)NSUB * NB * SCAP;             // N*ELL_W uint2    25.6 MB
    int*   cnt     = (int*)(ell + (size_t)N_NODES * ELL_W);      // N                 0.2 MB
    int*   btail   = cnt + N_NODES;                              // NSUB*NB*16        1.6 MB
    int*   ovf_n   = btail + NSUB * NB * BT_STRIDE;              // 1 (adjacent for single memset)
    int*   ovf_row = ovf_n + 1;
    int*   ovf_col = ovf_row + OVF_CAP;
    float* ovf_val = (float*)(ovf_col + OVF_CAP);

    dim3 blk(256);
    int gemmGrid = NL / 64;                   // 3125
    int partGrid = (E_NNZ + 255) / 256;       // 6250
    int ellGrid  = (NB + GROUP - 1) / GROUP;  // 782
    int spmmGrid = N_NODES * 64 / 256;        // 12500

    // All four scales' feat @ W in one shot, written into out (scratch; each slice
    // out[:,l,:] is consumed by scale-l spmm-1 strictly before scale-l spmm-2 overwrites it).
    gemm_all<<<gemmGrid, blk, 0, stream>>>(feat, W, out);

    for (int l = 0; l < L_SCALES; ++l) {
        // ---- Z = theta (.) (phi_inv_l @ out[:,l,:]) ----
        hipMemsetAsync(btail, 0, (NSUB * NB * BT_STRIDE + 1) * sizeof(int), stream);
        partition_edges<<<partGrid, blk, 0, stream>>>(
            pinv_idx + (size_t)l * 2 * E_NNZ,
            pinv_idx + (size_t)l * 2 * E_NNZ + E_NNZ,
            pinv_val + (size_t)l * E_NNZ,
            bkt, btail, ovf_n, ovf_row, ovf_col, ovf_val);
        ell_from_buckets<<<ellGrid, blk, 0, stream>>>(
            bkt, btail, ell, cnt, ovf_n, ovf_row, ovf_col, ovf_val);
        spmm_ell<<<spmmGrid, blk, 0, stream>>>(
            ell, cnt, ovf_n, ovf_row, ovf_col, ovf_val,
            out + (size_t)l * C, theta, Z, L_SCALES * C, C);

        // ---- out[:,l,:] = phi_l @ Z ----
        hipMemsetAsync(btail, 0, (NSUB * NB * BT_STRIDE + 1) * sizeof(int), stream);
        partition_edges<<<partGrid, blk, 0, stream>>>(
            phi_idx + (size_t)l * 2 * E_NNZ,
            phi_idx + (size_t)l * 2 * E_NNZ + E_NNZ,
            phi_val + (size_t)l * E_NNZ,
            bkt, btail, ovf_n, ovf_row, ovf_col, ovf_val);
        ell_from_buckets<<<ellGrid, blk, 0, stream>>>(
            bkt, btail, ell, cnt, ovf_n, ovf_row, ovf_col, ovf_val);
        spmm_ell<<<spmmGrid, blk, 0, stream>>>(
            ell, cnt, ovf_n, ovf_row, ovf_col, ovf_val,
            Z, nullptr, out + (size_t)l * C, C, L_SCALES * C);
    }
}

// Round 3
// 1862.198 us; speedup vs baseline: 1.2078x; 1.0638x over previous
//
#include <hip/hip_runtime.h>

#define N_NODES 50000
#define L_SCALES 4
#define E_NNZ 1600000
#define C 128
#define NL (N_NODES * L_SCALES)

#define ELL_W 64
#define OVF_CAP 8192

#define RPB 16                    // rows per bucket
#define NB (N_NODES / RPB)        // 3125 buckets (exact)
#define NSUB 8                    // per-XCD sub-regions
#define SCAP 112                  // capacity per (sub, bucket); mean 64, sigma 8
#define GROUP 4                   // buckets per workgroup in pass 2
#define BT_STRIDE 16              // pad tail counters to one per 64B line

// ---------------- Fused GEMM over all scales: Y[r,c] = sum_k feat[r,k]*W[k,c], r in [0, N*L) ----------------
// lane = row (64 rows/block shared by 4 waves), wave = 32-col slice.
// W reads are wave-uniform -> s_load (scalar pipe, free SGPR operand in v_fmac).
// Xs tile is XOR-swizzled on the 16B-slot index: byte = row*512 + 16*(slot ^ (row&31)).
// Bank check: per 32-lane phase, banks get exactly 4 accesses each (b128 minimum) on both
// the staging writes and the compute reads -> kills the 2.4e7 stride-512B conflicts of v2.
__global__ __launch_bounds__(256) void gemm_all(
    const float* __restrict__ feat,   // [NL, C]
    const float* __restrict__ W,      // [C, C]
    float* __restrict__ Y)            // [NL, C]  (aliases d_out)
{
    __shared__ float4 Xs4[64 * 32];   // 64 rows x 128 floats = 32 KB

    int t = threadIdx.x;
    int l = t & 63;                                  // lane = local row
    int c0 = __builtin_amdgcn_readfirstlane((t >> 6) << 5);  // wave's 32-col base (uniform)
    size_t r0 = (size_t)blockIdx.x * 64;             // NL/64 = 3125 blocks exact

    // Coalesced stage of the 64-row feature tile (float4), swizzled store
    const float4* feat4 = (const float4*)(feat + r0 * C);
    for (int i = t; i < 64 * 32; i += 256) {
        int row = i >> 5, slot = i & 31;
        Xs4[(row << 5) | (slot ^ (row & 31))] = feat4[i];
    }
    __syncthreads();

    float acc[32];
    #pragma unroll
    for (int j = 0; j < 32; ++j) acc[j] = 0.f;

    int m = l & 31;                                  // swizzle key for this lane's row
    for (int kt = 0; kt < C; kt += 8) {
        float4 xa = Xs4[(l << 5) | ((kt >> 2) ^ m)];
        float4 xb = Xs4[(l << 5) | (((kt >> 2) + 1) ^ m)];
        float x8[8];
        x8[0] = xa.x; x8[1] = xa.y; x8[2] = xa.z; x8[3] = xa.w;
        x8[4] = xb.x; x8[5] = xb.y; x8[6] = xb.z; x8[7] = xb.w;
        #pragma unroll
        for (int kk = 0; kk < 8; ++kk) {
            const float* wr = W + (size_t)(kt + kk) * C + c0;  // uniform -> s_load
            #pragma unroll
            for (int j = 0; j < 32; ++j)
                acc[j] = fmaf(x8[kk], wr[j], acc[j]);
        }
    }

    float* orow = Y + (r0 + l) * C + c0;
    #pragma unroll
    for (int j4 = 0; j4 < 8; ++j4)
        ((float4*)orow)[j4] = make_float4(acc[4*j4], acc[4*j4+1], acc[4*j4+2], acc[4*j4+3]);
}

// ---------------- Pass 1: partition edges into 16-row buckets, packed 8B records ----------------
__global__ __launch_bounds__(256) void partition_edges(
    const int*   __restrict__ rows,
    const int*   __restrict__ cols,
    const float* __restrict__ vals,
    uint2* __restrict__ bkt,          // [NSUB][NB][SCAP]
    int*   __restrict__ btail,        // [NSUB][NB] stride BT_STRIDE
    int* __restrict__ ovf_n, int* __restrict__ ovf_row,
    int* __restrict__ ovf_col, float* __restrict__ ovf_val)
{
    int e = blockIdx.x * 256 + threadIdx.x;
    if (e >= E_NNZ) return;
    int s = blockIdx.x & (NSUB - 1);  // heuristic XCD id: same-s blocks share an XCD L2
    int r = rows[e];
    int c = cols[e];
    float v = vals[e];
    int b = r >> 4;                   // RPB = 16
    int pos = atomicAdd(&btail[(s * NB + b) * BT_STRIDE], 1);
    if (pos < SCAP) {
        // col fits in 16 bits (N=50000 < 65536); rowlo in bits 16..19
        bkt[((size_t)s * NB + b) * SCAP + pos] =
            make_uint2((unsigned)c | ((unsigned)(r & (RPB - 1)) << 16), __float_as_uint(v));
    } else {                          // statistically never (z ~ 6 sigma); correctness fallback
        int k = atomicAdd(ovf_n, 1);
        if (k < OVF_CAP) { ovf_row[k] = r; ovf_col[k] = c; ovf_val[k] = v; }
    }
}

// ---------------- Pass 2: build packed ELL (uint2 {col, val}) in LDS, flush coalesced ----------------
__global__ __launch_bounds__(256) void ell_from_buckets(
    const uint2* __restrict__ bkt,
    const int*   __restrict__ btail,
    uint2* __restrict__ ell,          // [N][ELL_W]
    int*   __restrict__ cnt,          // [N]
    int* __restrict__ ovf_n, int* __restrict__ ovf_row,
    int* __restrict__ ovf_col, float* __restrict__ ovf_val)
{
    __shared__ __align__(16) uint2 ell_s[GROUP * RPB][ELL_W];   // 64 x 64 x 8B = 32 KB
    __shared__ int lcnt[GROUP * RPB];

    int t  = threadIdx.x;
    int b0 = blockIdx.x * GROUP;
    int r0 = b0 * RPB;

    if (t < GROUP * RPB) lcnt[t] = 0;
    __syncthreads();

    for (int g = 0; g < GROUP; ++g) {
        int b = b0 + g;
        if (b >= NB) break;           // grid covers 3128 buckets, NB=3125
        for (int s = 0; s < NSUB; ++s) {
            int n = btail[(s * NB + b) * BT_STRIDE];
            if (n > SCAP) n = SCAP;
            for (int i = t; i < n; i += 256) {
                uint2 rec = bkt[((size_t)s * NB + b) * SCAP + i];
                int lr = g * RPB + (int)(rec.x >> 16);
                int pos = atomicAdd(&lcnt[lr], 1);
                if (pos < ELL_W) {
                    ell_s[lr][pos] = make_uint2(rec.x & 0xFFFFu, rec.y);
                } else {              // row degree > 64: ~never (z ~ 5.7 sigma)
                    int k = atomicAdd(ovf_n, 1);
                    if (k < OVF_CAP) {
                        ovf_row[k] = r0 + lr;
                        ovf_col[k] = (int)(rec.x & 0xFFFFu);
                        ovf_val[k] = __uint_as_float(rec.y);
                    }
                }
            }
        }
    }
    __syncthreads();

    // Coalesced flush: 64 rows x 64 slots of uint2 = 32 KB, as uint4 (unused slots = don't-care,
    // spmm only broadcasts slots j < min(cnt, ELL_W)).
    const uint4* src = (const uint4*)&ell_s[0][0];
    for (int i = t; i < GROUP * RPB * (ELL_W / 2); i += 256) {   // 2048 uint4
        int row = r0 + (i >> 5);
        if (row < N_NODES)
            ((uint4*)ell)[(size_t)row * (ELL_W / 2) + (i & 31)] = src[i];
    }
    if (t < GROUP * RPB) {
        int row = r0 + t;
        if (row < N_NODES) cnt[row] = lcnt[t];
    }
}

// ---------------- SpMM (gather): out[row] = scale * sum_e val_e * X[col_e] ----------------
// readlane (not shfl): col/val become SGPRs -> scalar address path; 8 gathers in flight.
__global__ __launch_bounds__(256) void spmm_ell(
    const uint2* __restrict__ ell,
    const int*   __restrict__ cnt,
    const int*   __restrict__ ovf_n,
    const int*   __restrict__ ovf_row,
    const int*   __restrict__ ovf_col,
    const float* __restrict__ ovf_val,
    const float* __restrict__ X,          // row stride x_stride
    const float* __restrict__ row_scale,  // nullptr or theta[N]
    float*       __restrict__ out,        // row stride out_stride
    int x_stride, int out_stride)
{
    int row  = (blockIdx.x * 256 + threadIdx.x) >> 6;   // grid exact: 12500 wg x 4 rows
    int lane = threadIdx.x & 63;

    int n   = cnt[row];
    int ncl = n < ELL_W ? n : ELL_W;

    uint2 rec = make_uint2(0u, 0u);
    if (lane < ncl) rec = ell[(size_t)row * ELL_W + lane];  // masked: skip unused slots
    int mycol = (int)rec.x;
    int myval = (int)rec.y;

    float2 acc = {0.f, 0.f};
    int j = 0;
    for (; j + 8 <= ncl; j += 8) {
        float2 x[8];
        #pragma unroll
        for (int u = 0; u < 8; ++u) {
            int c = __builtin_amdgcn_readlane(mycol, j + u);   // SGPR col
            x[u] = ((const float2*)(X + (size_t)c * x_stride))[lane];
        }
        #pragma unroll
        for (int u = 0; u < 8; ++u) {
            float v = __uint_as_float((unsigned)__builtin_amdgcn_readlane(myval, j + u));
            acc.x = fmaf(v, x[u].x, acc.x);
            acc.y = fmaf(v, x[u].y, acc.y);
        }
    }
    for (; j < ncl; ++j) {
        int   c = __builtin_amdgcn_readlane(mycol, j);
        float v = __uint_as_float((unsigned)__builtin_amdgcn_readlane(myval, j));
        float2 x = ((const float2*)(X + (size_t)c * x_stride))[lane];
        acc.x = fmaf(v, x.x, acc.x);
        acc.y = fmaf(v, x.y, acc.y);
    }

    int m = *ovf_n;                    // expected 0; one hot scalar read per wave
    if (m > 0) {
        if (m > OVF_CAP) m = OVF_CAP;
        for (int k = 0; k < m; ++k) {
            if (ovf_row[k] == row) {
                float v = ovf_val[k];
                float2 x = ((const float2*)(X + (size_t)ovf_col[k] * x_stride))[lane];
                acc.x = fmaf(v, x.x, acc.x);
                acc.y = fmaf(v, x.y, acc.y);
            }
        }
    }

    if (row_scale) {
        float s = row_scale[row];
        acc.x *= s;
        acc.y *= s;
    }
    ((float2*)(out + (size_t)row * out_stride))[lane] = acc;
}

extern "C" void kernel_launch(void* const* d_in, const int* in_sizes, int n_in,
                              void* d_out, int out_size, void* d_ws, size_t ws_size,
                              hipStream_t stream) {
    const int*   phi_idx  = (const int*)  d_in[0];   // [L, 2, E]
    const float* phi_val  = (const float*)d_in[1];   // [L, E]
    const int*   pinv_idx = (const int*)  d_in[2];   // [L, 2, E]
    const float* pinv_val = (const float*)d_in[3];   // [L, E]
    const float* feat     = (const float*)d_in[4];   // [N, L, C] == [NL, C]
    const float* W        = (const float*)d_in[5];   // [C, C]
    const float* theta    = (const float*)d_in[6];   // [N]
    float* out = (float*)d_out;

    // Workspace layout (~75.5 MB)
    float* Z       = (float*)d_ws;                               // N*C f32          25.6 MB
    uint2* bkt     = (uint2*)(Z + (size_t)N_NODES * C);          // NSUB*NB*SCAP     22.4 MB
    uint2* ell     = bkt + (size_t)NSUB * NB * SCAP;             // N*ELL_W uint2    25.6 MB
    int*   cnt     = (int*)(ell + (size_t)N_NODES * ELL_W);      // N                 0.2 MB
    int*   btail   = cnt + N_NODES;                              // NSUB*NB*16        1.6 MB
    int*   ovf_n   = btail + NSUB * NB * BT_STRIDE;              // 1 (adjacent for single memset)
    int*   ovf_row = ovf_n + 1;
    int*   ovf_col = ovf_row + OVF_CAP;
    float* ovf_val = (float*)(ovf_col + OVF_CAP);

    dim3 blk(256);
    int gemmGrid = NL / 64;                   // 3125
    int partGrid = (E_NNZ + 255) / 256;       // 6250
    int ellGrid  = (NB + GROUP - 1) / GROUP;  // 782
    int spmmGrid = N_NODES * 64 / 256;        // 12500

    // All four scales' feat @ W in one shot, written into out (scratch; each slice
    // out[:,l,:] is consumed by scale-l spmm-1 strictly before scale-l spmm-2 overwrites it).
    gemm_all<<<gemmGrid, blk, 0, stream>>>(feat, W, out);

    for (int l = 0; l < L_SCALES; ++l) {
        // ---- Z = theta (.) (phi_inv_l @ out[:,l,:]) ----
        hipMemsetAsync(btail, 0, (NSUB * NB * BT_STRIDE + 1) * sizeof(int), stream);
        partition_edges<<<partGrid, blk, 0, stream>>>(
            pinv_idx + (size_t)l * 2 * E_NNZ,
            pinv_idx + (size_t)l * 2 * E_NNZ + E_NNZ,
            pinv_val + (size_t)l * E_NNZ,
            bkt, btail, ovf_n, ovf_row, ovf_col, ovf_val);
        ell_from_buckets<<<ellGrid, blk, 0, stream>>>(
            bkt, btail, ell, cnt, ovf_n, ovf_row, ovf_col, ovf_val);
        spmm_ell<<<spmmGrid, blk, 0, stream>>>(
            ell, cnt, ovf_n, ovf_row, ovf_col, ovf_val,
            out + (size_t)l * C, theta, Z, L_SCALES * C, C);

        // ---- out[:,l,:] = phi_l @ Z ----
        hipMemsetAsync(btail, 0, (NSUB * NB * BT_STRIDE + 1) * sizeof(int), stream);
        partition_edges<<<partGrid, blk, 0, stream>>>(
            phi_idx + (size_t)l * 2 * E_NNZ,
            phi_idx + (size_t)l * 2 * E_NNZ + E_NNZ,
            phi_val + (size_t)l * E_NNZ,
            bkt, btail, ovf_n, ovf_row, ovf_col, ovf_val);
        ell_from_buckets<<<ellGrid, blk, 0, stream>>>(
            bkt, btail, ell, cnt, ovf_n, ovf_row, ovf_col, ovf_val);
        spmm_ell<<<spmmGrid, blk, 0, stream>>>(
            ell, cnt, ovf_n, ovf_row, ovf_col, ovf_val,
            Z, nullptr, out + (size_t)l * C, C, L_SCALES * C);
    }
}